// Round 4
// baseline (695.516 us; speedup 1.0000x reference)
//
#include <hip/hip_runtime.h>
#include <math.h>

// Problem constants (B=2, H=W=256, DIM=INNER=64, WS=8, OWS=12, HEADS=4, DH=16)
#define NPIX   65536      // 256*256
#define NPIXT  131072     // B * NPIX
#define NW     1024       // 32*32 windows per batch
#define KEEP   512

// Layouts: x, condition_global, h1, sa, out = NCHW (as given / required).
// qs, ks, vs, amix = NHWC: t[(b*NPIX + p)*64 + c]  (64 contiguous ch/pixel).

// ---------------------------------------------------------------------------
// K1: fused q/k/v 1x1 convs.  Reads x NCHW (float4 over pixels), computes per
// pixel, writes NHWC (float4 over channels).
// ---------------------------------------------------------------------------
__global__ __launch_bounds__(256) void k_qkv(
    const float* __restrict__ x,
    const float* __restrict__ Wq, const float* __restrict__ bq,
    const float* __restrict__ Wk, const float* __restrict__ bk,
    const float* __restrict__ Wv, const float* __restrict__ bv,
    float* __restrict__ qs, float* __restrict__ ks, float* __restrict__ vs)
{
    __shared__ float xs[64][256];
    const int tid = threadIdx.x;
    const int gp  = blockIdx.x * 256 + tid;      // global pixel
    const int b   = gp >> 16;
    const int p   = gp & 65535;
    const int p0  = p & ~255;                    // block's first pixel

    // stage 64ch x 256px tile with float4 loads
    #pragma unroll
    for (int it = 0; it < 16; ++it) {
        const int i  = it * 256 + tid;           // 0..4095 float4s
        const int c  = i >> 6;
        const int p4 = i & 63;
        const float4 v = *(const float4*)(x + ((size_t)(b * 64 + c)) * NPIX + p0 + p4 * 4);
        *(float4*)&xs[c][p4 * 4] = v;
    }
    __syncthreads();

    const float* Ws[3]   = {Wq, Wk, Wv};
    const float* bias[3] = {bq, bk, bv};
    float* outs[3]       = {qs, ks, vs};

    #pragma unroll
    for (int m = 0; m < 3; ++m) {
        const float* W  = Ws[m];
        const float* bb = bias[m];
        float* o        = outs[m] + (size_t)gp * 64;
        for (int og = 0; og < 4; ++og) {
            float acc[16];
            #pragma unroll
            for (int j = 0; j < 16; ++j) acc[j] = 0.f;
            #pragma unroll 4
            for (int c = 0; c < 64; ++c) {
                const float xv = xs[c][tid];
                #pragma unroll
                for (int j = 0; j < 16; ++j)
                    acc[j] += W[(og * 16 + j) * 64 + c] * xv;
            }
            #pragma unroll
            for (int j4 = 0; j4 < 4; ++j4) {
                float4 v;
                v.x = acc[j4 * 4 + 0] + bb[og * 16 + j4 * 4 + 0];
                v.y = acc[j4 * 4 + 1] + bb[og * 16 + j4 * 4 + 1];
                v.z = acc[j4 * 4 + 2] + bb[og * 16 + j4 * 4 + 2];
                v.w = acc[j4 * 4 + 3] + bb[og * 16 + j4 * 4 + 3];
                *(float4*)(o + og * 16 + j4 * 4) = v;
            }
        }
    }
}

// ---------------------------------------------------------------------------
// K2: conditioning conv (68 -> 17) + channel LayerNorm + lrelu; emits xm.
// vs is NHWC -> float4 reads.  h1 stays NCHW (k_sa wants spatial planes).
// Accumulation order over c is unchanged (bit-identical scores -> partition).
// ---------------------------------------------------------------------------
__global__ __launch_bounds__(256) void k_cond(
    const float* __restrict__ vs, const float* __restrict__ cg,
    const float* __restrict__ pinW, const float* __restrict__ pinb,
    const float* __restrict__ lnw, const float* __restrict__ lnb,
    float* __restrict__ h1, float* __restrict__ xm)
{
    const int gp = blockIdx.x * 256 + threadIdx.x;
    const int b  = gp >> 16;
    const int p  = gp & 65535;
    const int h  = p >> 8;
    const int w  = p & 255;

    float acc[17];
    #pragma unroll
    for (int oc = 0; oc < 17; ++oc) acc[oc] = pinb[oc];

    const float* vp = vs + (size_t)gp * 64;
    #pragma unroll 4
    for (int c4 = 0; c4 < 16; ++c4) {
        const float4 v4 = *(const float4*)(vp + c4 * 4);
        const float vv[4] = {v4.x, v4.y, v4.z, v4.w};
        #pragma unroll
        for (int k = 0; k < 4; ++k) {
            const int c = c4 * 4 + k;
            #pragma unroll
            for (int oc = 0; oc < 17; ++oc)
                acc[oc] += pinW[oc * 68 + c] * vv[k];
        }
    }
    const float c64 = cg[(b * 2 + 0) * NPIX + p];
    const float c65 = cg[(b * 2 + 1) * NPIX + p];
    const float c66 = -1.f + 2.f * (float)(h & 7) / 7.f;
    const float c67 = -1.f + 2.f * (float)(w & 7) / 7.f;
    #pragma unroll
    for (int oc = 0; oc < 17; ++oc)
        acc[oc] += pinW[oc * 68 + 64] * c64 + pinW[oc * 68 + 65] * c65 +
                   pinW[oc * 68 + 66] * c66 + pinW[oc * 68 + 67] * c67;

    float u = 0.f;
    #pragma unroll
    for (int oc = 0; oc < 17; ++oc) u += acc[oc];
    u *= (1.f / 17.f);
    float s = 0.f;
    #pragma unroll
    for (int oc = 0; oc < 17; ++oc) { const float d = acc[oc] - u; s += d * d; }
    s *= (1.f / 17.f);
    const float rstd = rsqrtf(s + 1e-6f);

    float xsum = 0.f;
    #pragma unroll
    for (int oc = 0; oc < 17; ++oc) {
        float hv = lnw[oc] * (acc[oc] - u) * rstd + lnb[oc];
        hv = (hv >= 0.f) ? hv : 0.1f * hv;
        h1[(b * 17 + oc) * NPIX + p] = hv;
        xsum += hv;
    }
    xm[gp] = xsum * (1.f / 17.f);
}

// ---------------------------------------------------------------------------
// K3: 3x3 conv (17 -> 1) + sigmoid -> sa.  One block = one image row; stage
// 3 rows x 17 ch into LDS with float4 loads, taps from LDS.
// ---------------------------------------------------------------------------
__global__ __launch_bounds__(256) void k_sa(
    const float* __restrict__ h1, const float* __restrict__ saW,
    const float* __restrict__ sab, float* __restrict__ sa)
{
    __shared__ float S[17 * 3 * 256];
    const int tid = threadIdx.x;
    const int b   = blockIdx.x >> 8;
    const int row = blockIdx.x & 255;

    // stage: 17*3*64 = 3264 float4s
    for (int i = tid; i < 3264; i += 256) {
        const int ch  = i / 192;
        const int rem = i - ch * 192;
        const int dr  = rem >> 6;
        const int c4  = rem & 63;
        const int rr  = row + dr - 1;
        float4 v = {0.f, 0.f, 0.f, 0.f};
        if ((unsigned)rr < 256u)
            v = *(const float4*)(h1 + ((size_t)(b * 17 + ch)) * NPIX + rr * 256 + c4 * 4);
        *(float4*)&S[(ch * 3 + dr) * 256 + c4 * 4] = v;
    }
    __syncthreads();

    const int w = tid;
    float acc = sab[0];
    #pragma unroll 1
    for (int ch = 0; ch < 17; ++ch) {
        #pragma unroll
        for (int dr = 0; dr < 3; ++dr) {
            const float* Sp = &S[(ch * 3 + dr) * 256];
            const float m  = Sp[w];
            const float l  = (w > 0)   ? Sp[w - 1] : 0.f;
            const float r_ = (w < 255) ? Sp[w + 1] : 0.f;
            const float* Wp = saW + (ch * 3 + dr) * 3;
            acc += Wp[0] * l + Wp[1] * m + Wp[2] * r_;
        }
    }
    sa[b * NPIX + row * 256 + w] = 1.f / (1.f + __expf(-acc));
}

// ---------------------------------------------------------------------------
// K4: window scoring MLP + stable-argsort partition (rank_i = #{s_j > s_i} +
// #{j<i : s_j == s_i}; kept iff rank < 512).  One 1024-thr block per batch.
// Arithmetic identical to previous rounds (partition fidelity).
// ---------------------------------------------------------------------------
__global__ __launch_bounds__(1024) void k_score_select(
    const float* __restrict__ xm,
    const float* __restrict__ m1W, const float* __restrict__ m1b,
    const float* __restrict__ m2W, const float* __restrict__ m2b,
    int* __restrict__ flag, int* __restrict__ kept)
{
    __shared__ float sc[NW];
    const int b = blockIdx.x;
    const int t = threadIdx.x;
    const int i = t >> 5;
    const int j = t & 31;

    float z[8];
    #pragma unroll
    for (int jj = 0; jj < 8; ++jj) z[jj] = m1b[jj];

    for (int a = 0; a < 8; ++a) {
        #pragma unroll
        for (int cc = 0; cc < 8; ++cc) {
            const float xv = xm[b * NPIX + (i * 8 + a) * 256 + (j * 8 + cc)];
            const int tt = a * 8 + cc;
            #pragma unroll
            for (int jj = 0; jj < 8; ++jj)
                z[jj] += m1W[jj * 64 + tt] * xv;
        }
    }
    #pragma unroll
    for (int jj = 0; jj < 8; ++jj) z[jj] = (z[jj] >= 0.f) ? z[jj] : 0.1f * z[jj];

    float l0 = m2b[0], l1 = m2b[1];
    #pragma unroll
    for (int jj = 0; jj < 8; ++jj) { l0 += m2W[jj] * z[jj]; l1 += m2W[8 + jj] * z[jj]; }
    const float mx = fmaxf(l0, l1);
    const float e0 = expf(l0 - mx), e1 = expf(l1 - mx);
    sc[t] = e0 / (e0 + e1);
    __syncthreads();

    const float s = sc[t];
    int cnt = 0;
    for (int jq = 0; jq < NW; ++jq) {
        const float sj = sc[jq];
        cnt += (sj > s) || (sj == s && jq < t);
    }
    flag[b * NW + t] = (cnt < KEEP) ? 1 : 0;
    if (cnt < KEEP) kept[b * KEEP + cnt] = t;
}

// ---------------------------------------------------------------------------
// K5: windowed attention, NHWC, no LDS.  Block = 256 thr = 4 waves = the 4
// heads of one kept window.  Each wave loads its head's 12x12 K/V patch
// directly into registers in fragment layout (2 chunks of 72 keys; element
// (kp,d) -> reg[(kp&~3)>>2... i.e. reg kp/4, lane 16*(kp%4)+d) and broadcasts
// via v_readlane into the per-lane (per-query) dot products.  Key loop is
// row-major over the patch so every register / array index is compile-time.
// Single-pass softmax (no max shift; scores O(+-3)).  Output written to amix
// (aliases qs; each lane reads its q before writing the same bytes).
// ---------------------------------------------------------------------------
__global__ __launch_bounds__(256, 4) void k_attn(
    const float* __restrict__ qs, const float* __restrict__ ks,
    const float* __restrict__ vs, const int* __restrict__ kept,
    const float* __restrict__ relh, const float* __restrict__ relw,
    float* __restrict__ amix)
{
    const int b    = blockIdx.y;
    const int win  = kept[b * KEEP + blockIdx.x];
    const int wy = win >> 5, wx = win & 31;
    const int tid  = threadIdx.x;
    const int head = tid >> 6;
    const int lane = tid & 63;
    const int choff = head * 16;

    // ---- q (scaled), float4 NHWC ----
    const int qrow = lane >> 3, qcol = lane & 7;
    const size_t pix = (size_t)b * NPIX + (wy * 8 + qrow) * 256 + (wx * 8 + qcol);
    const float* qp = qs + pix * 64 + choff;
    float q[16];
    #pragma unroll
    for (int j4 = 0; j4 < 4; ++j4) {
        const float4 v = *(const float4*)(qp + j4 * 4);
        q[j4 * 4 + 0] = v.x * 0.25f; q[j4 * 4 + 1] = v.y * 0.25f;
        q[j4 * 4 + 2] = v.z * 0.25f; q[j4 * 4 + 3] = v.w * 0.25f;
    }

    // ---- rel-pos coefficients (float4 reads of the 16-wide tables) ----
    float cw[12], chh[12];
    #pragma unroll
    for (int k = 0; k < 12; ++k) {
        const float* rw = relw + (k - qcol + 11) * 16;
        const float* rh = relh + (k - qrow + 11) * 16;
        float sw = 0.f, sh = 0.f;
        #pragma unroll
        for (int j4 = 0; j4 < 4; ++j4) {
            const float4 w4 = *(const float4*)(rw + j4 * 4);
            const float4 h4 = *(const float4*)(rh + j4 * 4);
            sw += q[j4*4+0]*w4.x + q[j4*4+1]*w4.y + q[j4*4+2]*w4.z + q[j4*4+3]*w4.w;
            sh += q[j4*4+0]*h4.x + q[j4*4+1]*h4.y + q[j4*4+2]*h4.z + q[j4*4+3]*h4.w;
        }
        cw[k] = sw; chh[k] = sh;
    }

    // ---- fragment-lane decomposition for K/V loads ----
    const int sub = lane >> 4;       // kp % 4
    const int d_  = lane & 15;       // channel within head
    const int wy8 = wy * 8 - 2, wx8 = wx * 8 - 2;
    const size_t bbase = (size_t)b * NPIX;

    int kc = sub, kr = 0;            // incremental patch coords, step +4
    float sum = 0.f;
    float vo[16];
    #pragma unroll
    for (int d = 0; d < 16; ++d) vo[d] = 0.f;

    #pragma unroll
    for (int c = 0; c < 2; ++c) {
        // load chunk: keys 72c .. 72c+71
        float kreg[18], vreg[18];
        #pragma unroll
        for (int r = 0; r < 18; ++r) {
            const int ry = wy8 + kr;
            const int cx = wx8 + kc;
            const bool ok = ((unsigned)ry < 256u) && ((unsigned)cx < 256u);
            float kv = 0.f, vv = 0.f;
            if (ok) {
                const size_t g = (bbase + ry * 256 + cx) * 64 + choff + d_;
                kv = ks[g]; vv = vs[g];
            }
            kreg[r] = kv; vreg[r] = vv;
            kc += 4; if (kc >= 12) { kc -= 12; ++kr; }
        }
        // compute rows 6c .. 6c+5
        #pragma unroll
        for (int rl = 0; rl < 6; ++rl) {
            const float srow = chh[c * 6 + rl];
            #pragma unroll
            for (int col = 0; col < 12; ++col) {
                const int kl = rl * 12 + col;        // 0..71 (compile-time)
                const int r  = kl >> 2, kk = kl & 3;
                float s = srow + cw[col];
                #pragma unroll
                for (int d = 0; d < 16; ++d)
                    s += __int_as_float(__builtin_amdgcn_readlane(
                             __float_as_int(kreg[r]), kk * 16 + d)) * q[d];
                const float e = __expf(s);
                sum += e;
                #pragma unroll
                for (int d = 0; d < 16; ++d)
                    vo[d] += e * __int_as_float(__builtin_amdgcn_readlane(
                                 __float_as_int(vreg[r]), kk * 16 + d));
            }
        }
    }

    const float inv = 1.f / sum;
    float* op = amix + pix * 64 + choff;
    #pragma unroll
    for (int j4 = 0; j4 < 4; ++j4) {
        float4 v;
        v.x = vo[j4*4+0] * inv; v.y = vo[j4*4+1] * inv;
        v.z = vo[j4*4+2] * inv; v.w = vo[j4*4+3] * inv;
        *(float4*)(op + j4 * 4) = v;
    }
}

// ---------------------------------------------------------------------------
// K6: final 1x1 conv (64 -> 64) with fused easy path.  NHWC float4 reads ->
// LDS transpose -> per-pixel accumulate -> NCHW coalesced writes.
// ---------------------------------------------------------------------------
__global__ __launch_bounds__(256) void k_out_f(
    const float* __restrict__ amix, const float* __restrict__ vs,
    const float* __restrict__ sa, const int* __restrict__ flag,
    const float* __restrict__ W, const float* __restrict__ bias,
    float* __restrict__ out)
{
    __shared__ float xs[64][256];
    const int tid = threadIdx.x;
    const int gp  = blockIdx.x * 256 + tid;
    const int b   = gp >> 16;
    const int p   = gp & 65535;
    const int h   = p >> 8;
    const int w   = p & 255;

    const int win = (h >> 3) * 32 + (w >> 3);
    const int fl  = flag[b * NW + win];
    const float mult = fl ? 1.f : sa[gp];
    const float* src = (fl ? amix : vs) + (size_t)gp * 64;

    #pragma unroll
    for (int c4 = 0; c4 < 16; ++c4) {
        const float4 v = *(const float4*)(src + c4 * 4);
        xs[c4 * 4 + 0][tid] = v.x * mult;
        xs[c4 * 4 + 1][tid] = v.y * mult;
        xs[c4 * 4 + 2][tid] = v.z * mult;
        xs[c4 * 4 + 3][tid] = v.w * mult;
    }
    __syncthreads();

    const int base = (b << 6) * NPIX + p;
    for (int og = 0; og < 4; ++og) {
        float acc[16];
        #pragma unroll
        for (int j = 0; j < 16; ++j) acc[j] = 0.f;
        #pragma unroll 4
        for (int c = 0; c < 64; ++c) {
            const float xv = xs[c][tid];
            #pragma unroll
            for (int j = 0; j < 16; ++j)
                acc[j] += W[(og * 16 + j) * 64 + c] * xv;
        }
        #pragma unroll
        for (int j = 0; j < 16; ++j)
            out[base + (og * 16 + j) * NPIX] = acc[j] + bias[og * 16 + j];
    }
}

// ---------------------------------------------------------------------------
extern "C" void kernel_launch(void* const* d_in, const int* in_sizes, int n_in,
                              void* d_out, int out_size, void* d_ws, size_t ws_size,
                              hipStream_t stream)
{
    const float* x    = (const float*)d_in[0];
    const float* cg   = (const float*)d_in[1];
    const float* Wq   = (const float*)d_in[2];
    const float* bq   = (const float*)d_in[3];
    const float* Wk   = (const float*)d_in[4];
    const float* bk   = (const float*)d_in[5];
    const float* Wv   = (const float*)d_in[6];
    const float* bv   = (const float*)d_in[7];
    const float* Wout = (const float*)d_in[8];
    const float* bout = (const float*)d_in[9];
    const float* relh = (const float*)d_in[10];
    const float* relw = (const float*)d_in[11];
    const float* pinW = (const float*)d_in[12];
    const float* pinb = (const float*)d_in[13];
    const float* lnw  = (const float*)d_in[14];
    const float* lnb  = (const float*)d_in[15];
    const float* saW  = (const float*)d_in[16];
    const float* sab  = (const float*)d_in[17];
    const float* m1W  = (const float*)d_in[18];
    const float* m1b  = (const float*)d_in[19];
    const float* m2W  = (const float*)d_in[20];
    const float* m2b  = (const float*)d_in[21];
    float* out = (float*)d_out;

    // workspace layout (floats); qs doubles as the assembled "amix" tensor
    float* ws    = (float*)d_ws;
    float* qs    = ws;                       // 64*NPIXT (NHWC, aliased amix)
    float* ks    = qs + 8388608;             // NHWC
    float* vs    = ks + 8388608;             // NHWC
    float* h1    = vs + 8388608;             // 17 * NPIXT (NCHW)
    float* xm    = h1 + 17 * NPIXT;          // NPIXT
    float* sa    = xm + NPIXT;               // NPIXT
    int*   flag  = (int*)(sa + NPIXT);       // 2048
    int*   kept  = flag + 2048;              // 1024

    k_qkv         <<<NPIXT / 256, 256, 0, stream>>>(x, Wq, bq, Wk, bk, Wv, bv, qs, ks, vs);
    k_cond        <<<NPIXT / 256, 256, 0, stream>>>(vs, cg, pinW, pinb, lnw, lnb, h1, xm);
    k_sa          <<<512, 256, 0, stream>>>(h1, saW, sab, sa);
    k_score_select<<<2, 1024, 0, stream>>>(xm, m1W, m1b, m2W, m2b, flag, kept);
    k_attn        <<<dim3(KEEP, 2), 256, 0, stream>>>(qs, ks, vs, kept, relh, relw, qs);
    k_out_f       <<<NPIXT / 256, 256, 0, stream>>>(qs, vs, sa, flag, Wout, bout, out);
}

// Round 5
// 437.826 us; speedup vs baseline: 1.5886x; 1.5886x over previous
//
#include <hip/hip_runtime.h>
#include <math.h>

// Problem constants (B=2, H=W=256, DIM=INNER=64, WS=8, OWS=12, HEADS=4, DH=16)
#define NPIX   65536      // 256*256
#define NPIXT  131072     // B * NPIX
#define NW     1024       // 32*32 windows per batch
#define KEEP   512
#define PITCH  68         // LDS row pitch (floats): mult of 4 for float4 ops

// Layouts: x, condition_global, h1, sa, out = NCHW (as given / required).
// qs, ks, vs, amix = NHWC: t[(b*NPIX + p)*64 + c]  (64 contiguous ch/pixel).

// ---------------------------------------------------------------------------
// K1: fused q/k/v 1x1 convs.  Reads x NCHW (float4 over pixels), computes per
// pixel, writes NHWC (float4 over channels).  Loop nest og -> c -> (m,j) so
// each LDS x value is read 4x (not 12x); accumulation order over c per
// (m,og,j) is ascending, bit-identical to prior rounds (partition fidelity).
// ---------------------------------------------------------------------------
__global__ __launch_bounds__(256) void k_qkv(
    const float* __restrict__ x,
    const float* __restrict__ Wq, const float* __restrict__ bq,
    const float* __restrict__ Wk, const float* __restrict__ bk,
    const float* __restrict__ Wv, const float* __restrict__ bv,
    float* __restrict__ qs, float* __restrict__ ks, float* __restrict__ vs)
{
    __shared__ float xs[64][256];
    const int tid = threadIdx.x;
    const int gp  = blockIdx.x * 256 + tid;      // global pixel
    const int b   = gp >> 16;
    const int p   = gp & 65535;
    const int p0  = p & ~255;                    // block's first pixel

    #pragma unroll
    for (int it = 0; it < 16; ++it) {
        const int i  = it * 256 + tid;           // 0..4095 float4s
        const int c  = i >> 6;
        const int p4 = i & 63;
        const float4 v = *(const float4*)(x + ((size_t)(b * 64 + c)) * NPIX + p0 + p4 * 4);
        *(float4*)&xs[c][p4 * 4] = v;
    }
    __syncthreads();

    const float* Ws[3]   = {Wq, Wk, Wv};
    const float* bias[3] = {bq, bk, bv};
    float* outs[3] = {qs + (size_t)gp * 64, ks + (size_t)gp * 64, vs + (size_t)gp * 64};

    for (int og = 0; og < 4; ++og) {
        float acc[3][16];
        #pragma unroll
        for (int m = 0; m < 3; ++m)
            #pragma unroll
            for (int j = 0; j < 16; ++j) acc[m][j] = 0.f;

        #pragma unroll 2
        for (int c = 0; c < 64; ++c) {
            const float xv = xs[c][tid];
            #pragma unroll
            for (int m = 0; m < 3; ++m) {
                const float* W = Ws[m];
                #pragma unroll
                for (int j = 0; j < 16; ++j)
                    acc[m][j] += W[(og * 16 + j) * 64 + c] * xv;
            }
        }
        #pragma unroll
        for (int m = 0; m < 3; ++m) {
            const float* bb = bias[m];
            #pragma unroll
            for (int j4 = 0; j4 < 4; ++j4) {
                float4 v;
                v.x = acc[m][j4 * 4 + 0] + bb[og * 16 + j4 * 4 + 0];
                v.y = acc[m][j4 * 4 + 1] + bb[og * 16 + j4 * 4 + 1];
                v.z = acc[m][j4 * 4 + 2] + bb[og * 16 + j4 * 4 + 2];
                v.w = acc[m][j4 * 4 + 3] + bb[og * 16 + j4 * 4 + 3];
                *(float4*)(outs[m] + og * 16 + j4 * 4) = v;
            }
        }
    }
}

// ---------------------------------------------------------------------------
// K2: conditioning conv (68 -> 17) + channel LayerNorm + lrelu; emits xm.
// vs is NHWC -> float4 reads.  h1 stays NCHW.  Accumulation order over c
// unchanged (bit-identical scores -> partition).
// ---------------------------------------------------------------------------
__global__ __launch_bounds__(256) void k_cond(
    const float* __restrict__ vs, const float* __restrict__ cg,
    const float* __restrict__ pinW, const float* __restrict__ pinb,
    const float* __restrict__ lnw, const float* __restrict__ lnb,
    float* __restrict__ h1, float* __restrict__ xm)
{
    const int gp = blockIdx.x * 256 + threadIdx.x;
    const int b  = gp >> 16;
    const int p  = gp & 65535;
    const int h  = p >> 8;
    const int w  = p & 255;

    float acc[17];
    #pragma unroll
    for (int oc = 0; oc < 17; ++oc) acc[oc] = pinb[oc];

    const float* vp = vs + (size_t)gp * 64;
    #pragma unroll 4
    for (int c4 = 0; c4 < 16; ++c4) {
        const float4 v4 = *(const float4*)(vp + c4 * 4);
        const float vv[4] = {v4.x, v4.y, v4.z, v4.w};
        #pragma unroll
        for (int k = 0; k < 4; ++k) {
            const int c = c4 * 4 + k;
            #pragma unroll
            for (int oc = 0; oc < 17; ++oc)
                acc[oc] += pinW[oc * 68 + c] * vv[k];
        }
    }
    const float c64 = cg[(b * 2 + 0) * NPIX + p];
    const float c65 = cg[(b * 2 + 1) * NPIX + p];
    const float c66 = -1.f + 2.f * (float)(h & 7) / 7.f;
    const float c67 = -1.f + 2.f * (float)(w & 7) / 7.f;
    #pragma unroll
    for (int oc = 0; oc < 17; ++oc)
        acc[oc] += pinW[oc * 68 + 64] * c64 + pinW[oc * 68 + 65] * c65 +
                   pinW[oc * 68 + 66] * c66 + pinW[oc * 68 + 67] * c67;

    float u = 0.f;
    #pragma unroll
    for (int oc = 0; oc < 17; ++oc) u += acc[oc];
    u *= (1.f / 17.f);
    float s = 0.f;
    #pragma unroll
    for (int oc = 0; oc < 17; ++oc) { const float d = acc[oc] - u; s += d * d; }
    s *= (1.f / 17.f);
    const float rstd = rsqrtf(s + 1e-6f);

    float xsum = 0.f;
    #pragma unroll
    for (int oc = 0; oc < 17; ++oc) {
        float hv = lnw[oc] * (acc[oc] - u) * rstd + lnb[oc];
        hv = (hv >= 0.f) ? hv : 0.1f * hv;
        h1[(b * 17 + oc) * NPIX + p] = hv;
        xsum += hv;
    }
    xm[gp] = xsum * (1.f / 17.f);
}

// ---------------------------------------------------------------------------
// K3: 3x3 conv (17 -> 1) + sigmoid -> sa.  One block = one image row; stage
// 3 rows x 17 ch into LDS with float4 loads, taps from LDS.
// ---------------------------------------------------------------------------
__global__ __launch_bounds__(256) void k_sa(
    const float* __restrict__ h1, const float* __restrict__ saW,
    const float* __restrict__ sab, float* __restrict__ sa)
{
    __shared__ float S[17 * 3 * 256];
    const int tid = threadIdx.x;
    const int b   = blockIdx.x >> 8;
    const int row = blockIdx.x & 255;

    for (int i = tid; i < 3264; i += 256) {
        const int ch  = i / 192;
        const int rem = i - ch * 192;
        const int dr  = rem >> 6;
        const int c4  = rem & 63;
        const int rr  = row + dr - 1;
        float4 v = {0.f, 0.f, 0.f, 0.f};
        if ((unsigned)rr < 256u)
            v = *(const float4*)(h1 + ((size_t)(b * 17 + ch)) * NPIX + rr * 256 + c4 * 4);
        *(float4*)&S[(ch * 3 + dr) * 256 + c4 * 4] = v;
    }
    __syncthreads();

    const int w = tid;
    float acc = sab[0];
    #pragma unroll 1
    for (int ch = 0; ch < 17; ++ch) {
        #pragma unroll
        for (int dr = 0; dr < 3; ++dr) {
            const float* Sp = &S[(ch * 3 + dr) * 256];
            const float m  = Sp[w];
            const float l  = (w > 0)   ? Sp[w - 1] : 0.f;
            const float r_ = (w < 255) ? Sp[w + 1] : 0.f;
            const float* Wp = saW + (ch * 3 + dr) * 3;
            acc += Wp[0] * l + Wp[1] * m + Wp[2] * r_;
        }
    }
    sa[b * NPIX + row * 256 + w] = 1.f / (1.f + __expf(-acc));
}

// ---------------------------------------------------------------------------
// K4: window scoring MLP + stable-argsort partition (rank_i = #{s_j > s_i} +
// #{j<i : s_j == s_i}; kept iff rank < 512).  One 1024-thr block per batch.
// Arithmetic identical to previous rounds (partition fidelity).
// ---------------------------------------------------------------------------
__global__ __launch_bounds__(1024) void k_score_select(
    const float* __restrict__ xm,
    const float* __restrict__ m1W, const float* __restrict__ m1b,
    const float* __restrict__ m2W, const float* __restrict__ m2b,
    int* __restrict__ flag, int* __restrict__ kept)
{
    __shared__ float sc[NW];
    const int b = blockIdx.x;
    const int t = threadIdx.x;
    const int i = t >> 5;
    const int j = t & 31;

    float z[8];
    #pragma unroll
    for (int jj = 0; jj < 8; ++jj) z[jj] = m1b[jj];

    for (int a = 0; a < 8; ++a) {
        #pragma unroll
        for (int cc = 0; cc < 8; ++cc) {
            const float xv = xm[b * NPIX + (i * 8 + a) * 256 + (j * 8 + cc)];
            const int tt = a * 8 + cc;
            #pragma unroll
            for (int jj = 0; jj < 8; ++jj)
                z[jj] += m1W[jj * 64 + tt] * xv;
        }
    }
    #pragma unroll
    for (int jj = 0; jj < 8; ++jj) z[jj] = (z[jj] >= 0.f) ? z[jj] : 0.1f * z[jj];

    float l0 = m2b[0], l1 = m2b[1];
    #pragma unroll
    for (int jj = 0; jj < 8; ++jj) { l0 += m2W[jj] * z[jj]; l1 += m2W[8 + jj] * z[jj]; }
    const float mx = fmaxf(l0, l1);
    const float e0 = expf(l0 - mx), e1 = expf(l1 - mx);
    sc[t] = e0 / (e0 + e1);
    __syncthreads();

    const float s = sc[t];
    int cnt = 0;
    for (int jq = 0; jq < NW; ++jq) {
        const float sj = sc[jq];
        cnt += (sj > s) || (sj == s && jq < t);
    }
    flag[b * NW + t] = (cnt < KEEP) ? 1 : 0;
    if (cnt < KEEP) kept[b * KEEP + cnt] = t;
}

// ---------------------------------------------------------------------------
// K5: windowed attention.  Block = 256 thr = 4 waves = 4 heads of one kept
// window.  ALL global traffic is cooperative + contiguous (full 128B lines):
//   phase 0: q window staged to LDS (2 KB row bursts), lanes read q[16];
//   chunks c=0,1: 6 patch rows of K and V staged to LDS (3 KB row bursts),
//     each wave redistributes its head's 72-key fragment to registers
//     (element (kp,d) -> reg[kp/4], lane 16*(kp%4)+d) and runs the
//     readlane-broadcast QK/exp/PV core (all indices compile-time);
//   epilogue: vo -> LDS transpose -> cooperative float4 stores (2 KB bursts).
// Single-pass softmax, no max shift (scores O(+-3)).  amix aliases qs: q is
// consumed in phase 0, stores land at the very end, same-block addresses only.
// ---------------------------------------------------------------------------
__global__ __launch_bounds__(256, 4) void k_attn(
    const float* __restrict__ qs, const float* __restrict__ ks,
    const float* __restrict__ vs, const int* __restrict__ kept,
    const float* __restrict__ relh, const float* __restrict__ relw,
    float* __restrict__ amix)
{
    __shared__ float SK[72 * PITCH];   // 19584 B
    __shared__ float SV[72 * PITCH];   // 19584 B

    const int b    = blockIdx.y;
    const int win  = kept[b * KEEP + blockIdx.x];
    const int wy = win >> 5, wx = win & 31;
    const int tid  = threadIdx.x;
    const int head = tid >> 6;
    const int lane = tid & 63;
    const int choff = head * 16;
    const size_t bbase = (size_t)b * NPIX;
    const int px0 = (wy * 8) * 256 + wx * 8;      // window origin pixel

    // ---- phase 0: cooperative q stage (64 px x 64 ch = 1024 float4) ----
    #pragma unroll
    for (int it = 0; it < 4; ++it) {
        const int i  = it * 256 + tid;
        const int px = i >> 4;
        const int c4 = i & 15;
        const float4 v = *(const float4*)(
            qs + (bbase + px0 + (px >> 3) * 256 + (px & 7)) * 64 + c4 * 4);
        *(float4*)&SK[px * PITCH + c4 * 4] = v;
    }
    __syncthreads();

    const int qrow = lane >> 3, qcol = lane & 7;
    float q[16];
    #pragma unroll
    for (int j4 = 0; j4 < 4; ++j4) {
        const float4 v = *(const float4*)&SK[(qrow * 8 + qcol) * PITCH + choff + j4 * 4];
        q[j4 * 4 + 0] = v.x * 0.25f; q[j4 * 4 + 1] = v.y * 0.25f;
        q[j4 * 4 + 2] = v.z * 0.25f; q[j4 * 4 + 3] = v.w * 0.25f;
    }

    // ---- rel-pos coefficients (small cached tables) ----
    float cw[12], chh[12];
    #pragma unroll
    for (int k = 0; k < 12; ++k) {
        const float* rw = relw + (k - qcol + 11) * 16;
        const float* rh = relh + (k - qrow + 11) * 16;
        float sw = 0.f, sh = 0.f;
        #pragma unroll
        for (int j4 = 0; j4 < 4; ++j4) {
            const float4 w4 = *(const float4*)(rw + j4 * 4);
            const float4 h4 = *(const float4*)(rh + j4 * 4);
            sw += q[j4*4+0]*w4.x + q[j4*4+1]*w4.y + q[j4*4+2]*w4.z + q[j4*4+3]*w4.w;
            sh += q[j4*4+0]*h4.x + q[j4*4+1]*h4.y + q[j4*4+2]*h4.z + q[j4*4+3]*h4.w;
        }
        cw[k] = sw; chh[k] = sh;
    }

    const int sub = lane >> 4;       // kp % 4
    const int d_  = lane & 15;       // channel within head
    const int wy8 = wy * 8 - 2, wx8 = wx * 8 - 2;

    float sum = 0.f;
    float vo[16];
    #pragma unroll
    for (int d = 0; d < 16; ++d) vo[d] = 0.f;

    #pragma unroll 1
    for (int c = 0; c < 2; ++c) {
        __syncthreads();    // prior LDS reads complete before restaging
        // ---- stage 6 patch rows of K and V (each 72 px x 64 ch) ----
        for (int i = tid; i < 1152; i += 256) {
            const int pxl = i >> 4;             // 0..71
            const int c4  = i & 15;
            const int rl  = pxl / 12;
            const int col = pxl - rl * 12;
            const int ry  = wy8 + 6 * c + rl;
            const int cx  = wx8 + col;
            float4 kv = {0.f,0.f,0.f,0.f}, vv = {0.f,0.f,0.f,0.f};
            if ((unsigned)ry < 256u && (unsigned)cx < 256u) {
                const size_t g = (bbase + ry * 256 + cx) * 64 + c4 * 4;
                kv = *(const float4*)(ks + g);
                vv = *(const float4*)(vs + g);
            }
            *(float4*)&SK[pxl * PITCH + c4 * 4] = kv;
            *(float4*)&SV[pxl * PITCH + c4 * 4] = vv;
        }
        __syncthreads();

        // ---- redistribute this head's 72-key fragment ----
        float kreg[18], vreg[18];
        #pragma unroll
        for (int r = 0; r < 18; ++r) {
            const int a = (4 * r + sub) * PITCH + choff + d_;
            kreg[r] = SK[a];
            vreg[r] = SV[a];
        }

        // ---- QK + exp + PV over 72 keys (rows 6c..6c+5) ----
        #pragma unroll
        for (int rl = 0; rl < 6; ++rl) {
            const float srow = chh[c * 6 + rl];
            #pragma unroll
            for (int col = 0; col < 12; ++col) {
                const int kl = rl * 12 + col;        // 0..71 compile-time
                const int r  = kl >> 2, kk = kl & 3;
                float s = srow + cw[col];
                #pragma unroll
                for (int d = 0; d < 16; ++d)
                    s += __int_as_float(__builtin_amdgcn_readlane(
                             __float_as_int(kreg[r]), kk * 16 + d)) * q[d];
                const float e = __expf(s);
                sum += e;
                #pragma unroll
                for (int d = 0; d < 16; ++d)
                    vo[d] += e * __int_as_float(__builtin_amdgcn_readlane(
                                 __float_as_int(vreg[r]), kk * 16 + d));
            }
        }
    }

    // ---- epilogue: normalize, transpose via LDS, contiguous stores ----
    const float inv = 1.f / sum;
    __syncthreads();
    #pragma unroll
    for (int j4 = 0; j4 < 4; ++j4) {
        float4 v;
        v.x = vo[j4*4+0] * inv; v.y = vo[j4*4+1] * inv;
        v.z = vo[j4*4+2] * inv; v.w = vo[j4*4+3] * inv;
        *(float4*)&SK[(qrow * 8 + qcol) * PITCH + choff + j4 * 4] = v;
    }
    __syncthreads();
    #pragma unroll
    for (int it = 0; it < 4; ++it) {
        const int i  = it * 256 + tid;
        const int px = i >> 4;
        const int c4 = i & 15;
        const float4 v = *(const float4*)&SK[px * PITCH + c4 * 4];
        *(float4*)(amix + (bbase + px0 + (px >> 3) * 256 + (px & 7)) * 64 + c4 * 4) = v;
    }
}

// ---------------------------------------------------------------------------
// K6: final 1x1 conv (64 -> 64) with fused easy path.  NHWC float4 reads ->
// LDS transpose -> per-pixel accumulate -> NCHW coalesced writes.
// ---------------------------------------------------------------------------
__global__ __launch_bounds__(256) void k_out_f(
    const float* __restrict__ amix, const float* __restrict__ vs,
    const float* __restrict__ sa, const int* __restrict__ flag,
    const float* __restrict__ W, const float* __restrict__ bias,
    float* __restrict__ out)
{
    __shared__ float xs[64][256];
    const int tid = threadIdx.x;
    const int gp  = blockIdx.x * 256 + tid;
    const int b   = gp >> 16;
    const int p   = gp & 65535;
    const int h   = p >> 8;
    const int w   = p & 255;

    const int win = (h >> 3) * 32 + (w >> 3);
    const int fl  = flag[b * NW + win];
    const float mult = fl ? 1.f : sa[gp];
    const float* src = (fl ? amix : vs) + (size_t)gp * 64;

    #pragma unroll
    for (int c4 = 0; c4 < 16; ++c4) {
        const float4 v = *(const float4*)(src + c4 * 4);
        xs[c4 * 4 + 0][tid] = v.x * mult;
        xs[c4 * 4 + 1][tid] = v.y * mult;
        xs[c4 * 4 + 2][tid] = v.z * mult;
        xs[c4 * 4 + 3][tid] = v.w * mult;
    }
    __syncthreads();

    const int base = (b << 6) * NPIX + p;
    for (int og = 0; og < 4; ++og) {
        float acc[16];
        #pragma unroll
        for (int j = 0; j < 16; ++j) acc[j] = 0.f;
        #pragma unroll 4
        for (int c = 0; c < 64; ++c) {
            const float xv = xs[c][tid];
            #pragma unroll
            for (int j = 0; j < 16; ++j)
                acc[j] += W[(og * 16 + j) * 64 + c] * xv;
        }
        #pragma unroll
        for (int j = 0; j < 16; ++j)
            out[base + (og * 16 + j) * NPIX] = acc[j] + bias[og * 16 + j];
    }
}

// ---------------------------------------------------------------------------
extern "C" void kernel_launch(void* const* d_in, const int* in_sizes, int n_in,
                              void* d_out, int out_size, void* d_ws, size_t ws_size,
                              hipStream_t stream)
{
    const float* x    = (const float*)d_in[0];
    const float* cg   = (const float*)d_in[1];
    const float* Wq   = (const float*)d_in[2];
    const float* bq   = (const float*)d_in[3];
    const float* Wk   = (const float*)d_in[4];
    const float* bk   = (const float*)d_in[5];
    const float* Wv   = (const float*)d_in[6];
    const float* bv   = (const float*)d_in[7];
    const float* Wout = (const float*)d_in[8];
    const float* bout = (const float*)d_in[9];
    const float* relh = (const float*)d_in[10];
    const float* relw = (const float*)d_in[11];
    const float* pinW = (const float*)d_in[12];
    const float* pinb = (const float*)d_in[13];
    const float* lnw  = (const float*)d_in[14];
    const float* lnb  = (const float*)d_in[15];
    const float* saW  = (const float*)d_in[16];
    const float* sab  = (const float*)d_in[17];
    const float* m1W  = (const float*)d_in[18];
    const float* m1b  = (const float*)d_in[19];
    const float* m2W  = (const float*)d_in[20];
    const float* m2b  = (const float*)d_in[21];
    float* out = (float*)d_out;

    // workspace layout (floats); qs doubles as the assembled "amix" tensor
    float* ws    = (float*)d_ws;
    float* qs    = ws;                       // 64*NPIXT (NHWC, aliased amix)
    float* ks    = qs + 8388608;             // NHWC
    float* vs    = ks + 8388608;             // NHWC
    float* h1    = vs + 8388608;             // 17 * NPIXT (NCHW)
    float* xm    = h1 + 17 * NPIXT;          // NPIXT
    float* sa    = xm + NPIXT;               // NPIXT
    int*   flag  = (int*)(sa + NPIXT);       // 2048
    int*   kept  = flag + 2048;              // 1024

    k_qkv         <<<NPIXT / 256, 256, 0, stream>>>(x, Wq, bq, Wk, bk, Wv, bv, qs, ks, vs);
    k_cond        <<<NPIXT / 256, 256, 0, stream>>>(vs, cg, pinW, pinb, lnw, lnb, h1, xm);
    k_sa          <<<512, 256, 0, stream>>>(h1, saW, sab, sa);
    k_score_select<<<2, 1024, 0, stream>>>(xm, m1W, m1b, m2W, m2b, flag, kept);
    k_attn        <<<dim3(KEEP, 2), 256, 0, stream>>>(qs, ks, vs, kept, relh, relw, qs);
    k_out_f       <<<NPIXT / 256, 256, 0, stream>>>(qs, vs, sa, flag, Wout, bout, out);
}